// Round 15
// baseline (195.688 us; speedup 1.0000x reference)
//
#include <hip/hip_runtime.h>

// SOM loss, MI355X — FP8 GEMM, k-permuted layout, 3-buffer LDS, 1 barrier/K-tile,
// staging overlapped with MFMA. B=4096, D=1024, m=n=128, T=100.
// Xf8/Wf8 stored with within-64B-block byte permutation s = ((k>>3)&1)*32 + (k>>4)*8 + (k&7)
// so MFMA fragments are contiguous 16B chunks (ds_read_b128 at floor). Same perm on X and W
// => dot products unchanged.
// ws layout:
//   Xf8  fp8[4096][1024]         @ 0           (4 MB)
//   Wf8  fp8[16384][1024]        @ 4194304     (16 MB)
//   x2   f32[4096]               @ 20971520
//   w2   f32[16384]              @ 20987904
//   d2   bf16[4096][16384]       @ 21053440    (128 MB)
//   pmin f32[4096][128]          @ 155271168
//   pidx i32[4096][128]          @ 157368320
//   lossb f32[4096]              @ 159465472

typedef __attribute__((ext_vector_type(8))) short short8;
typedef __attribute__((ext_vector_type(16))) float f32x16;
typedef __attribute__((ext_vector_type(2))) long i64x2;
typedef unsigned short ushort_t;

#define B_ROWS 4096
#define DIM    1024
#define MN     16384
#define NJB    128

__device__ static inline ushort_t f32_to_bf16(float f) {
    unsigned u = __float_as_uint(f);
    u = (u + 0x7FFFu + ((u >> 16) & 1u)) >> 16;   // RTN-even
    return (ushort_t)u;
}
__device__ static inline float bf16_to_f32(ushort_t h) {
    return __uint_as_float(((unsigned)h) << 16);
}
__device__ static inline void gload_lds16(const void* g, void* l) {
    __builtin_amdgcn_global_load_lds(
        (const __attribute__((address_space(1))) unsigned*)g,
        (__attribute__((address_space(3))) unsigned*)l, 16, 0, 0);
}

// ---------- Kernel 1: f32 -> fp8(e4m3), k-permuted store + row sum-of-squares ----------
__global__ __launch_bounds__(256) void k_convert(
    const float* __restrict__ X, const float* __restrict__ W,
    unsigned char* __restrict__ Xf8, unsigned char* __restrict__ Wf8,
    float* __restrict__ x2, float* __restrict__ w2) {
    int row  = blockIdx.x * 4 + (threadIdx.x >> 6);
    int lane = threadIdx.x & 63;
    const float4* src;
    int* dst;
    float* sq;
    if (row < B_ROWS) {
        src = (const float4*)(X + (size_t)row * DIM);
        dst = (int*)(Xf8 + (size_t)row * DIM);
        sq  = x2 + row;
    } else {
        int r2 = row - B_ROWS;
        src = (const float4*)(W + (size_t)r2 * DIM);
        dst = (int*)(Wf8 + (size_t)r2 * DIM);
        sq  = w2 + r2;
    }
    const int t4 = lane >> 4;
    const int Foff = ((lane >> 3) & 1) * 2 + ((lane >> 1) & 3) * 4 + (lane & 1);
    float s = 0.f;
    #pragma unroll
    for (int c = 0; c < 4; ++c) {
        int F = (c * 4 + t4) * 16 + Foff;     // float4 index of permuted source
        float4 v = src[F];
        s += v.x * v.x + v.y * v.y + v.z * v.z + v.w * v.w;
        int r = __builtin_amdgcn_cvt_pk_fp8_f32(v.x, v.y, 0, false);
        r     = __builtin_amdgcn_cvt_pk_fp8_f32(v.z, v.w, r, true);
        dst[c * 64 + lane] = r;
    }
    #pragma unroll
    for (int d = 1; d < 64; d <<= 1) s += __shfl_xor(s, d);
    if (lane == 0) *sq = s;
}

// ---------- Kernel 2: 256x128-tile FP8 GEMM (v_mfma_f32_32x32x16_fp8_fp8) ----------
// 512 thr = 8 waves (4M x 2N), wave tile 64x64 (acc 64 f32 AGPR). K-tile 64 fp8.
// THREE LDS buffers (3 x 24KB), fully-unrolled K-loop (buffer index compile-time,
// zero rotor registers). Per kt: frag reads (buf kt%3) -> STAGE kt+2 (buf (kt+2)%3,
// dead since prev iter) -> lgkm(4) -> MFMA ks01 -> lgkm(0) -> MFMA ks23 ->
// vmcnt(3) [kt+1 landed, kt+2 in flight] -> ONE barrier. Staging drains under MFMA.
__global__ __launch_bounds__(512, 3) void k_gemm(
    const unsigned char* __restrict__ Xf8, const unsigned char* __restrict__ Wf8,
    const float* __restrict__ x2, const float* __restrict__ w2,
    ushort_t* __restrict__ d2, float* __restrict__ pmin, int* __restrict__ pidx) {
    __shared__ __attribute__((aligned(1024))) unsigned char ldsb[73728];

    const int tid  = threadIdx.x;
    const int lane = tid & 63;
    const int w    = tid >> 6;
    const int wrM  = w >> 1;      // 0..3  (X-row quarter of 256)
    const int wcN  = w & 1;       // 0..1  (W-col half of 128)
    const int l31  = lane & 31;
    const int h    = lane >> 5;   // k-half

    // XCD-bijective block swizzle (2048 % 8 == 0)
    const int bid = blockIdx.x;
    const int swz = (bid & 7) * 256 + (bid >> 3);
    const int tn  = swz >> 4;     // 0..127  W-tile (128 cols)
    const int tm  = swz & 15;     // 0..15   X-tile (256 rows)

    const size_t aRow = (size_t)tm * 256;
    const size_t bRow = (size_t)tn * 128;

    // staging source precompute (inverse-swizzled)
    const unsigned char* srcA0; const unsigned char* srcA1; const unsigned char* srcB0;
    {
        int p, crow, lcol;
        p = tid * 16; crow = p >> 7; lcol = (p & 127) ^ ((crow & 7) << 4);
        srcA0 = Xf8 + (aRow + crow * 2 + (lcol >> 6)) * DIM + (lcol & 63);
        p = 8192 + tid * 16; crow = p >> 7; lcol = (p & 127) ^ ((crow & 7) << 4);
        srcA1 = Xf8 + (aRow + crow * 2 + (lcol >> 6)) * DIM + (lcol & 63);
        p = tid * 16; crow = p >> 7; lcol = (p & 127) ^ ((crow & 7) << 4);
        srcB0 = Wf8 + (bRow + crow * 2 + (lcol >> 6)) * DIM + (lcol & 63);
    }

    #define STAGE(kt, bb) do {                                                   \
        gload_lds16(srcA0 + (kt) * 64, ldsb + (bb) + tid * 16);                  \
        gload_lds16(srcA1 + (kt) * 64, ldsb + (bb) + 8192 + tid * 16);           \
        gload_lds16(srcB0 + (kt) * 64, ldsb + (bb) + 16384 + tid * 16);          \
    } while (0)

    // fragment addressing: row r = base + l31; composite crow = r>>1;
    // stored offset in composite = (r&1)*64 + h*32 + q*16, XOR ((crow&7)<<4).
    const int rA0  = wrM * 64 + l31;
    const int rB0  = wcN * 64 + l31;
    const int fb   = (l31 & 1) * 64 + h * 32;
    const int aA0 = (rA0 >> 1) * 128 + ((fb)      ^ (((rA0 >> 1) & 7) << 4));
    const int aA1 = (rA0 >> 1) * 128 + ((fb + 16) ^ (((rA0 >> 1) & 7) << 4));
    const int aB0 = 16384 + (rB0 >> 1) * 128 + ((fb)      ^ (((rB0 >> 1) & 7) << 4));
    const int aB1 = 16384 + (rB0 >> 1) * 128 + ((fb + 16) ^ (((rB0 >> 1) & 7) << 4));

    f32x16 acc[2][2];
    #pragma unroll
    for (int i = 0; i < 2; ++i)
        #pragma unroll
        for (int j = 0; j < 2; ++j) acc[i][j] = (f32x16)0.f;

    #define BAR() __builtin_amdgcn_s_barrier()
    #define SCB() __builtin_amdgcn_sched_barrier(0)

    // prologue: T0 -> b0, T1 -> b1
    STAGE(0, 0);
    STAGE(1, 24576);
    asm volatile("s_waitcnt vmcnt(3)" ::: "memory");   // T0 landed (T1 in flight)
    SCB();
    BAR();

    #pragma unroll
    for (int kt = 0; kt < 16; ++kt) {
        const int bb = (kt % 3) * 24576;          // compile-time (full unroll)
        const int bs = ((kt + 2) % 3) * 24576;    // staging target: dead buffer
        i64x2 xq0[2], xq1[2], wq0[2], wq1[2];
        #pragma unroll
        for (int mi = 0; mi < 2; ++mi) {
            xq0[mi] = *(const i64x2*)(ldsb + bb + aA0 + mi * 2048);
            xq1[mi] = *(const i64x2*)(ldsb + bb + aA1 + mi * 2048);
        }
        #pragma unroll
        for (int ni = 0; ni < 2; ++ni) {
            wq0[ni] = *(const i64x2*)(ldsb + bb + aB0 + ni * 2048);
            wq1[ni] = *(const i64x2*)(ldsb + bb + aB1 + ni * 2048);
        }
        if (kt < 14) STAGE(kt + 2, bs);           // issues under MFMA below
        asm volatile("s_waitcnt lgkmcnt(4)" ::: "memory");
        SCB();
        __builtin_amdgcn_s_setprio(1);
        #pragma unroll
        for (int mi = 0; mi < 2; ++mi)
            #pragma unroll
            for (int ni = 0; ni < 2; ++ni) {
                acc[mi][ni] = __builtin_amdgcn_mfma_f32_32x32x16_fp8_fp8(
                    wq0[ni][0], xq0[mi][0], acc[mi][ni], 0, 0, 0);   // ks0
                acc[mi][ni] = __builtin_amdgcn_mfma_f32_32x32x16_fp8_fp8(
                    wq0[ni][1], xq0[mi][1], acc[mi][ni], 0, 0, 0);   // ks1
            }
        __builtin_amdgcn_s_setprio(0);
        asm volatile("s_waitcnt lgkmcnt(0)" ::: "memory");
        SCB();
        __builtin_amdgcn_s_setprio(1);
        #pragma unroll
        for (int mi = 0; mi < 2; ++mi)
            #pragma unroll
            for (int ni = 0; ni < 2; ++ni) {
                acc[mi][ni] = __builtin_amdgcn_mfma_f32_32x32x16_fp8_fp8(
                    wq1[ni][0], xq1[mi][0], acc[mi][ni], 0, 0, 0);   // ks2
                acc[mi][ni] = __builtin_amdgcn_mfma_f32_32x32x16_fp8_fp8(
                    wq1[ni][1], xq1[mi][1], acc[mi][ni], 0, 0, 0);   // ks3
            }
        __builtin_amdgcn_s_setprio(0);
        SCB();
        if (kt < 14)       asm volatile("s_waitcnt vmcnt(3)" ::: "memory"); // kt+1 landed
        else if (kt == 14) asm volatile("s_waitcnt vmcnt(0)" ::: "memory"); // kt=15 landed
        SCB();
        BAR();   // single barrier: kt+1 visible; all reads of restage-target drained
    }

    // ---- epilogue: d2 = x2 - 2*dot + w2 -> bf16, LDS-transposed coalesced store ----
    // D layout (32x32, shape-determined): col = l31 (X-row), row = (reg&3)+8*(reg>>2)
    // +4*h (W-col). per-wave 8KB: [xr:64][128B], col-byte XOR ((xr&7)<<4)
    unsigned char* wls = ldsb + w * 8192;
    const int colw = tn * 128 + wcN * 64;
    const int rowbase = tm * 256 + wrM * 64;
    float4 w2q[2][4];
    #pragma unroll
    for (int ni = 0; ni < 2; ++ni)
        #pragma unroll
        for (int q = 0; q < 4; ++q)
            w2q[ni][q] = *(const float4*)(w2 + colw + ni * 32 + q * 8 + h * 4);

    float mnA[2]; int ixA[2];
    #pragma unroll
    for (int mi = 0; mi < 2; ++mi) {
        const int xr = mi * 32 + l31;
        const float xx = x2[rowbase + xr];
        float mn = __builtin_inff(); int ix = 0x7fffffff;
        #pragma unroll
        for (int ni = 0; ni < 2; ++ni) {
            #pragma unroll
            for (int q = 0; q < 4; ++q) {
                float dv[4];
                ushort4 st;
                #pragma unroll
                for (int t = 0; t < 4; ++t) {
                    dv[t] = xx - 2.f * acc[mi][ni][q * 4 + t] + w2q[ni][q][t];
                    st[t] = (unsigned short)f32_to_bf16(dv[t]);
                }
                *(ushort4*)(wls + xr * 128
                            + ((ni * 64 + q * 16 + h * 8) ^ ((xr & 7) << 4))) = st;
                #pragma unroll
                for (int t = 0; t < 4; ++t) {
                    const int cand = colw + ni * 32 + q * 8 + h * 4 + t;
                    if (dv[t] < mn || (dv[t] == mn && cand < ix)) { mn = dv[t]; ix = cand; }
                }
            }
        }
        float om = __shfl_xor(mn, 32);
        int   oi = __shfl_xor(ix, 32);
        if (om < mn || (om == mn && oi < ix)) { mn = om; ix = oi; }
        mnA[mi] = mn; ixA[mi] = ix;
    }
    asm volatile("s_waitcnt lgkmcnt(0)" ::: "memory");  // wave-private LDS writes done
    SCB();
    // read back transposed: 8 lanes x 16B = 128B contiguous per d2 row
    #pragma unroll
    for (int j = 0; j < 8; ++j) {
        const int rl = j * 8 + (lane >> 3);      // row_local 0..63
        const int cb = (lane & 7) * 16;
        short8 v = *(const short8*)(wls + rl * 128 + (cb ^ ((rl & 7) << 4)));
        *(short8*)((char*)(d2 + (size_t)(rowbase + rl) * MN + colw) + cb) = v;
    }
    __syncthreads();
    // per-row argmin partials across the 2 N-waves
    float* smin = (float*)ldsb;            // [256][2]
    int*   sidx = (int*)(ldsb + 2048);     // [256][2]
    if (lane < 32) {
        #pragma unroll
        for (int mi = 0; mi < 2; ++mi) {
            const int rloc = wrM * 64 + mi * 32 + l31;
            smin[rloc * 2 + wcN] = mnA[mi];
            sidx[rloc * 2 + wcN] = ixA[mi];
        }
    }
    __syncthreads();
    if (tid < 256) {
        float m0 = smin[tid * 2];     int i0 = sidx[tid * 2];
        float m1 = smin[tid * 2 + 1]; int i1 = sidx[tid * 2 + 1];
        bool take1 = (m1 < m0) || (m1 == m0 && i1 < i0);
        const int row = tm * 256 + tid;
        pmin[(size_t)row * NJB + tn] = take1 ? m1 : m0;
        pidx[(size_t)row * NJB + tn] = take1 ? i1 : i0;
    }
    #undef STAGE
    #undef BAR
    #undef SCB
}

// ---------- Kernel 3: fused argmin-finish + influence-weighted row sum ----------
__global__ __launch_bounds__(256) void k_loss(
    const ushort_t* __restrict__ d2, const float* __restrict__ pmin,
    const int* __restrict__ pidx, float* __restrict__ lossb) {
    __shared__ float etab[255];
    __shared__ float red[4];
    __shared__ int bmu_s;
    int t = threadIdx.x;
    if (t < 255) etab[t] = __expf(-(float)(t * t) * 1e-4f);  // exp(-r^2/T^2), T=100
    int row = blockIdx.x;
    if (t < 64) {
        float m0 = pmin[(size_t)row * NJB + t];
        int   i0 = pidx[(size_t)row * NJB + t];
        float m1 = pmin[(size_t)row * NJB + t + 64];
        int   i1 = pidx[(size_t)row * NJB + t + 64];
        if (m1 < m0 || (m1 == m0 && i1 < i0)) { m0 = m1; i0 = i1; }
        #pragma unroll
        for (int d = 1; d < 64; d <<= 1) {
            float om = __shfl_xor(m0, d);
            int   oi = __shfl_xor(i0, d);
            if (om < m0 || (om == m0 && oi < i0)) { m0 = om; i0 = oi; }
        }
        if (t == 0) bmu_s = i0;
    }
    __syncthreads();
    int bl = bmu_s;
    int bi = bl >> 7, bj = bl & 127;
    const ushort_t* dr = d2 + (size_t)row * MN;
    float s = 0.f;
    #pragma unroll
    for (int c = 0; c < 8; ++c) {
        int j = c * 2048 + t * 8;
        short8 v = *(const short8*)&dr[j];
        int di = abs((j >> 7) - bi);
        int jc = j & 127;
        #pragma unroll
        for (int u = 0; u < 8; ++u) {
            int mh = di + abs(jc + u - bj);
            s += bf16_to_f32((ushort_t)v[u]) * etab[mh];
        }
    }
    #pragma unroll
    for (int d = 1; d < 64; d <<= 1) s += __shfl_xor(s, d);
    if ((t & 63) == 0) red[t >> 6] = s;
    __syncthreads();
    if (t == 0) lossb[row] = red[0] + red[1] + red[2] + red[3];
}

// ---------- Kernel 4: final deterministic reduce ----------
__global__ __launch_bounds__(256) void k_final(
    const float* __restrict__ lossb, float* __restrict__ out) {
    __shared__ float red[4];
    int t = threadIdx.x;
    float s = 0.f;
    #pragma unroll
    for (int k = 0; k < 16; ++k) s += lossb[t + k * 256];
    #pragma unroll
    for (int d = 1; d < 64; d <<= 1) s += __shfl_xor(s, d);
    if ((t & 63) == 0) red[t >> 6] = s;
    __syncthreads();
    if (t == 0) out[0] = (red[0] + red[1] + red[2] + red[3]) * (1.0f / 128.0f);
}

extern "C" void kernel_launch(void* const* d_in, const int* in_sizes, int n_in,
                              void* d_out, int out_size, void* d_ws, size_t ws_size,
                              hipStream_t stream) {
    const float* X = (const float*)d_in[0];
    const float* W = (const float*)d_in[1];
    unsigned char* ws = (unsigned char*)d_ws;
    unsigned char* Xf8 = ws;
    unsigned char* Wf8 = ws + 4194304;
    float*    x2   = (float*)(ws + 20971520);
    float*    w2   = (float*)(ws + 20987904);
    ushort_t* d2   = (ushort_t*)(ws + 21053440);
    float*    pmin = (float*)(ws + 155271168);
    int*      pidx = (int*)(ws + 157368320);
    float*    lossb= (float*)(ws + 159465472);

    k_convert<<<5120, 256, 0, stream>>>(X, W, Xf8, Wf8, x2, w2);
    k_gemm<<<2048, 512, 0, stream>>>(Xf8, Wf8, x2, w2, d2, pmin, pidx);
    k_loss<<<4096, 256, 0, stream>>>(d2, pmin, pidx, lossb);
    k_final<<<1, 256, 0, stream>>>(lossb, (float*)d_out);
}

// Round 16
// 158.623 us; speedup vs baseline: 1.2337x; 1.2337x over previous
//
#include <hip/hip_runtime.h>

// SOM loss, MI355X — FP8 GEMM, k-permuted layout, compiler-scheduled K-loop
// (no setprio / no manual lgkm waits / no sched_barrier in the hot loop).
// B=4096, D=1024, m=n=128, T=100.
// Xf8/Wf8 stored with within-64B-block byte permutation s = ((k>>3)&1)*32 + (k>>4)*8 + (k&7)
// so MFMA fragments are contiguous 16B chunks (ds_read_b128 at floor). Same perm on X and W
// => dot products unchanged.
// ws layout:
//   Xf8  fp8[4096][1024]         @ 0           (4 MB)
//   Wf8  fp8[16384][1024]        @ 4194304     (16 MB)
//   x2   f32[4096]               @ 20971520
//   w2   f32[16384]              @ 20987904
//   d2   bf16[4096][16384]       @ 21053440    (128 MB)
//   pmin f32[4096][128]          @ 155271168
//   pidx i32[4096][128]          @ 157368320
//   lossb f32[4096]              @ 159465472

typedef __attribute__((ext_vector_type(8))) short short8;
typedef __attribute__((ext_vector_type(16))) float f32x16;
typedef __attribute__((ext_vector_type(2))) long i64x2;
typedef unsigned short ushort_t;

#define B_ROWS 4096
#define DIM    1024
#define MN     16384
#define NJB    128

__device__ static inline ushort_t f32_to_bf16(float f) {
    unsigned u = __float_as_uint(f);
    u = (u + 0x7FFFu + ((u >> 16) & 1u)) >> 16;   // RTN-even
    return (ushort_t)u;
}
__device__ static inline float bf16_to_f32(ushort_t h) {
    return __uint_as_float(((unsigned)h) << 16);
}
__device__ static inline void gload_lds16(const void* g, void* l) {
    __builtin_amdgcn_global_load_lds(
        (const __attribute__((address_space(1))) unsigned*)g,
        (__attribute__((address_space(3))) unsigned*)l, 16, 0, 0);
}

// ---------- Kernel 1: f32 -> fp8(e4m3), k-permuted store + row sum-of-squares ----------
__global__ __launch_bounds__(256) void k_convert(
    const float* __restrict__ X, const float* __restrict__ W,
    unsigned char* __restrict__ Xf8, unsigned char* __restrict__ Wf8,
    float* __restrict__ x2, float* __restrict__ w2) {
    int row  = blockIdx.x * 4 + (threadIdx.x >> 6);
    int lane = threadIdx.x & 63;
    const float4* src;
    int* dst;
    float* sq;
    if (row < B_ROWS) {
        src = (const float4*)(X + (size_t)row * DIM);
        dst = (int*)(Xf8 + (size_t)row * DIM);
        sq  = x2 + row;
    } else {
        int r2 = row - B_ROWS;
        src = (const float4*)(W + (size_t)r2 * DIM);
        dst = (int*)(Wf8 + (size_t)r2 * DIM);
        sq  = w2 + r2;
    }
    const int t4 = lane >> 4;
    const int Foff = ((lane >> 3) & 1) * 2 + ((lane >> 1) & 3) * 4 + (lane & 1);
    float s = 0.f;
    #pragma unroll
    for (int c = 0; c < 4; ++c) {
        int F = (c * 4 + t4) * 16 + Foff;     // float4 index of permuted source
        float4 v = src[F];
        s += v.x * v.x + v.y * v.y + v.z * v.z + v.w * v.w;
        int r = __builtin_amdgcn_cvt_pk_fp8_f32(v.x, v.y, 0, false);
        r     = __builtin_amdgcn_cvt_pk_fp8_f32(v.z, v.w, r, true);
        dst[c * 64 + lane] = r;
    }
    #pragma unroll
    for (int d = 1; d < 64; d <<= 1) s += __shfl_xor(s, d);
    if (lane == 0) *sq = s;
}

// ---------- Kernel 2: 256x128-tile FP8 GEMM (v_mfma_f32_32x32x16_fp8_fp8) ----------
// 512 thr = 8 waves (4M x 2N), wave tile 64x64 (acc 64 f32 AGPR). K-tile 64 fp8.
// LDS: 2 dbuf x 24KB, composite 128B rows, XOR ((crow&7)<<4). 16 K-tiles.
// Hot loop is COMPILER-SCHEDULED: plain ds_reads (q0 group then q1 group) and
// MFMAs; the compiler inserts minimal counted lgkmcnt waits so q1's reads drain
// under q0's MFMA cluster (m97/m141: hand-pinning with sched_barrier+setprio
// serializes; removed). Only cross-wave gates kept: BAR / STAGE / vmcnt(3) / BAR.
__global__ __launch_bounds__(512, 3) void k_gemm(
    const unsigned char* __restrict__ Xf8, const unsigned char* __restrict__ Wf8,
    const float* __restrict__ x2, const float* __restrict__ w2,
    ushort_t* __restrict__ d2, float* __restrict__ pmin, int* __restrict__ pidx) {
    __shared__ __attribute__((aligned(1024))) unsigned char ldsb[65536];

    const int tid  = threadIdx.x;
    const int lane = tid & 63;
    const int w    = tid >> 6;
    const int wrM  = w >> 1;      // 0..3  (X-row quarter of 256)
    const int wcN  = w & 1;       // 0..1  (W-col half of 128)
    const int l31  = lane & 31;
    const int h    = lane >> 5;   // k-half

    // XCD-bijective block swizzle (2048 % 8 == 0)
    const int bid = blockIdx.x;
    const int swz = (bid & 7) * 256 + (bid >> 3);
    const int tn  = swz >> 4;     // 0..127  W-tile (128 cols)
    const int tm  = swz & 15;     // 0..15   X-tile (256 rows)

    const size_t aRow = (size_t)tm * 256;
    const size_t bRow = (size_t)tn * 128;

    // staging source precompute (inverse-swizzled)
    const unsigned char* srcA0; const unsigned char* srcA1; const unsigned char* srcB0;
    {
        int p, crow, lcol;
        p = tid * 16; crow = p >> 7; lcol = (p & 127) ^ ((crow & 7) << 4);
        srcA0 = Xf8 + (aRow + crow * 2 + (lcol >> 6)) * DIM + (lcol & 63);
        p = 8192 + tid * 16; crow = p >> 7; lcol = (p & 127) ^ ((crow & 7) << 4);
        srcA1 = Xf8 + (aRow + crow * 2 + (lcol >> 6)) * DIM + (lcol & 63);
        p = tid * 16; crow = p >> 7; lcol = (p & 127) ^ ((crow & 7) << 4);
        srcB0 = Wf8 + (bRow + crow * 2 + (lcol >> 6)) * DIM + (lcol & 63);
    }

    #define STAGE(kt, buf) do {                                                  \
        gload_lds16(srcA0 + (kt) * 64, ldsb + (buf) * 24576 + tid * 16);         \
        gload_lds16(srcA1 + (kt) * 64, ldsb + (buf) * 24576 + 8192 + tid * 16);  \
        gload_lds16(srcB0 + (kt) * 64, ldsb + (buf) * 24576 + 16384 + tid * 16); \
    } while (0)

    // fragment addressing: row r = base + l31; composite crow = r>>1;
    // stored offset in composite = (r&1)*64 + h*32 + q*16, XOR ((crow&7)<<4).
    const int rA0  = wrM * 64 + l31;
    const int rB0  = wcN * 64 + l31;
    const int fb   = (l31 & 1) * 64 + h * 32;
    const int aA0 = (rA0 >> 1) * 128 + ((fb)      ^ (((rA0 >> 1) & 7) << 4));
    const int aA1 = (rA0 >> 1) * 128 + ((fb + 16) ^ (((rA0 >> 1) & 7) << 4));
    const int aB0 = 16384 + (rB0 >> 1) * 128 + ((fb)      ^ (((rB0 >> 1) & 7) << 4));
    const int aB1 = 16384 + (rB0 >> 1) * 128 + ((fb + 16) ^ (((rB0 >> 1) & 7) << 4));

    f32x16 acc[2][2];
    #pragma unroll
    for (int i = 0; i < 2; ++i)
        #pragma unroll
        for (int j = 0; j < 2; ++j) acc[i][j] = (f32x16)0.f;

    #define BAR() __builtin_amdgcn_s_barrier()

    // prologue: T0 -> buf0, T1 -> buf1
    STAGE(0, 0);
    STAGE(1, 1);
    asm volatile("s_waitcnt vmcnt(3)" ::: "memory");   // T0 landed (T1 in flight)
    BAR();

    for (int kt = 0; kt < 16; ++kt) {
        const int bb = (kt & 1) * 24576;
        i64x2 xq0[2], xq1[2], wq0[2], wq1[2];
        // q0 group first, q1 group second — compiler schedules counted waits
        #pragma unroll
        for (int mi = 0; mi < 2; ++mi)
            xq0[mi] = *(const i64x2*)(ldsb + bb + aA0 + mi * 2048);
        #pragma unroll
        for (int ni = 0; ni < 2; ++ni)
            wq0[ni] = *(const i64x2*)(ldsb + bb + aB0 + ni * 2048);
        #pragma unroll
        for (int mi = 0; mi < 2; ++mi)
            xq1[mi] = *(const i64x2*)(ldsb + bb + aA1 + mi * 2048);
        #pragma unroll
        for (int ni = 0; ni < 2; ++ni)
            wq1[ni] = *(const i64x2*)(ldsb + bb + aB1 + ni * 2048);
        // MFMA q0 (needs only q0 regs) — q1 reads drain underneath
        #pragma unroll
        for (int mi = 0; mi < 2; ++mi)
            #pragma unroll
            for (int ni = 0; ni < 2; ++ni) {
                acc[mi][ni] = __builtin_amdgcn_mfma_f32_32x32x16_fp8_fp8(
                    wq0[ni][0], xq0[mi][0], acc[mi][ni], 0, 0, 0);   // ks0
                acc[mi][ni] = __builtin_amdgcn_mfma_f32_32x32x16_fp8_fp8(
                    wq0[ni][1], xq0[mi][1], acc[mi][ni], 0, 0, 0);   // ks1
            }
        // MFMA q1
        #pragma unroll
        for (int mi = 0; mi < 2; ++mi)
            #pragma unroll
            for (int ni = 0; ni < 2; ++ni) {
                acc[mi][ni] = __builtin_amdgcn_mfma_f32_32x32x16_fp8_fp8(
                    wq1[ni][0], xq1[mi][0], acc[mi][ni], 0, 0, 0);   // ks2
                acc[mi][ni] = __builtin_amdgcn_mfma_f32_32x32x16_fp8_fp8(
                    wq1[ni][1], xq1[mi][1], acc[mi][ni], 0, 0, 0);   // ks3
            }
        BAR();   // all waves' reads of bb consumed (MFMA deps force drain)
        if (kt < 14) {
            STAGE(kt + 2, kt & 1);
            asm volatile("s_waitcnt vmcnt(3)" ::: "memory");  // kt+1 landed
            BAR();
        } else if (kt == 14) {
            asm volatile("s_waitcnt vmcnt(0)" ::: "memory");  // kt=15 landed
            BAR();
        }
    }

    // ---- epilogue: d2 = x2 - 2*dot + w2 -> bf16, LDS-transposed coalesced store ----
    // D layout (32x32, shape-determined): col = l31 (X-row), row = (reg&3)+8*(reg>>2)
    // +4*h (W-col). per-wave 8KB: [xr:64][128B], col-byte XOR ((xr&7)<<4)
    unsigned char* wls = ldsb + w * 8192;
    const int colw = tn * 128 + wcN * 64;
    const int rowbase = tm * 256 + wrM * 64;
    float4 w2q[2][4];
    #pragma unroll
    for (int ni = 0; ni < 2; ++ni)
        #pragma unroll
        for (int q = 0; q < 4; ++q)
            w2q[ni][q] = *(const float4*)(w2 + colw + ni * 32 + q * 8 + h * 4);

    float mnA[2]; int ixA[2];
    #pragma unroll
    for (int mi = 0; mi < 2; ++mi) {
        const int xr = mi * 32 + l31;
        const float xx = x2[rowbase + xr];
        float mn = __builtin_inff(); int ix = 0x7fffffff;
        #pragma unroll
        for (int ni = 0; ni < 2; ++ni) {
            #pragma unroll
            for (int q = 0; q < 4; ++q) {
                float dv[4];
                ushort4 st;
                #pragma unroll
                for (int t = 0; t < 4; ++t) {
                    dv[t] = xx - 2.f * acc[mi][ni][q * 4 + t] + w2q[ni][q][t];
                    st[t] = (unsigned short)f32_to_bf16(dv[t]);
                }
                *(ushort4*)(wls + xr * 128
                            + ((ni * 64 + q * 16 + h * 8) ^ ((xr & 7) << 4))) = st;
                #pragma unroll
                for (int t = 0; t < 4; ++t) {
                    const int cand = colw + ni * 32 + q * 8 + h * 4 + t;
                    if (dv[t] < mn || (dv[t] == mn && cand < ix)) { mn = dv[t]; ix = cand; }
                }
            }
        }
        float om = __shfl_xor(mn, 32);
        int   oi = __shfl_xor(ix, 32);
        if (om < mn || (om == mn && oi < ix)) { mn = om; ix = oi; }
        mnA[mi] = mn; ixA[mi] = ix;
    }
    // read back transposed: 8 lanes x 16B = 128B contiguous per d2 row
    // (compiler inserts the lgkm waits for the write->read dependency)
    #pragma unroll
    for (int j = 0; j < 8; ++j) {
        const int rl = j * 8 + (lane >> 3);      // row_local 0..63
        const int cb = (lane & 7) * 16;
        short8 v = *(const short8*)(wls + rl * 128 + (cb ^ ((rl & 7) << 4)));
        *(short8*)((char*)(d2 + (size_t)(rowbase + rl) * MN + colw) + cb) = v;
    }
    __syncthreads();
    // per-row argmin partials across the 2 N-waves
    float* smin = (float*)ldsb;            // [256][2]
    int*   sidx = (int*)(ldsb + 2048);     // [256][2]
    if (lane < 32) {
        #pragma unroll
        for (int mi = 0; mi < 2; ++mi) {
            const int rloc = wrM * 64 + mi * 32 + l31;
            smin[rloc * 2 + wcN] = mnA[mi];
            sidx[rloc * 2 + wcN] = ixA[mi];
        }
    }
    __syncthreads();
    if (tid < 256) {
        float m0 = smin[tid * 2];     int i0 = sidx[tid * 2];
        float m1 = smin[tid * 2 + 1]; int i1 = sidx[tid * 2 + 1];
        bool take1 = (m1 < m0) || (m1 == m0 && i1 < i0);
        const int row = tm * 256 + tid;
        pmin[(size_t)row * NJB + tn] = take1 ? m1 : m0;
        pidx[(size_t)row * NJB + tn] = take1 ? i1 : i0;
    }
    #undef STAGE
    #undef BAR
}

// ---------- Kernel 3: fused argmin-finish + influence-weighted row sum ----------
__global__ __launch_bounds__(256) void k_loss(
    const ushort_t* __restrict__ d2, const float* __restrict__ pmin,
    const int* __restrict__ pidx, float* __restrict__ lossb) {
    __shared__ float etab[255];
    __shared__ float red[4];
    __shared__ int bmu_s;
    int t = threadIdx.x;
    if (t < 255) etab[t] = __expf(-(float)(t * t) * 1e-4f);  // exp(-r^2/T^2), T=100
    int row = blockIdx.x;
    if (t < 64) {
        float m0 = pmin[(size_t)row * NJB + t];
        int   i0 = pidx[(size_t)row * NJB + t];
        float m1 = pmin[(size_t)row * NJB + t + 64];
        int   i1 = pidx[(size_t)row * NJB + t + 64];
        if (m1 < m0 || (m1 == m0 && i1 < i0)) { m0 = m1; i0 = i1; }
        #pragma unroll
        for (int d = 1; d < 64; d <<= 1) {
            float om = __shfl_xor(m0, d);
            int   oi = __shfl_xor(i0, d);
            if (om < m0 || (om == m0 && oi < i0)) { m0 = om; i0 = oi; }
        }
        if (t == 0) bmu_s = i0;
    }
    __syncthreads();
    int bl = bmu_s;
    int bi = bl >> 7, bj = bl & 127;
    const ushort_t* dr = d2 + (size_t)row * MN;
    float s = 0.f;
    #pragma unroll
    for (int c = 0; c < 8; ++c) {
        int j = c * 2048 + t * 8;
        short8 v = *(const short8*)&dr[j];
        int di = abs((j >> 7) - bi);
        int jc = j & 127;
        #pragma unroll
        for (int u = 0; u < 8; ++u) {
            int mh = di + abs(jc + u - bj);
            s += bf16_to_f32((ushort_t)v[u]) * etab[mh];
        }
    }
    #pragma unroll
    for (int d = 1; d < 64; d <<= 1) s += __shfl_xor(s, d);
    if ((t & 63) == 0) red[t >> 6] = s;
    __syncthreads();
    if (t == 0) lossb[row] = red[0] + red[1] + red[2] + red[3];
}

// ---------- Kernel 4: final deterministic reduce ----------
__global__ __launch_bounds__(256) void k_final(
    const float* __restrict__ lossb, float* __restrict__ out) {
    __shared__ float red[4];
    int t = threadIdx.x;
    float s = 0.f;
    #pragma unroll
    for (int k = 0; k < 16; ++k) s += lossb[t + k * 256];
    #pragma unroll
    for (int d = 1; d < 64; d <<= 1) s += __shfl_xor(s, d);
    if ((t & 63) == 0) red[t >> 6] = s;
    __syncthreads();
    if (t == 0) out[0] = (red[0] + red[1] + red[2] + red[3]) * (1.0f / 128.0f);
}

extern "C" void kernel_launch(void* const* d_in, const int* in_sizes, int n_in,
                              void* d_out, int out_size, void* d_ws, size_t ws_size,
                              hipStream_t stream) {
    const float* X = (const float*)d_in[0];
    const float* W = (const float*)d_in[1];
    unsigned char* ws = (unsigned char*)d_ws;
    unsigned char* Xf8 = ws;
    unsigned char* Wf8 = ws + 4194304;
    float*    x2   = (float*)(ws + 20971520);
    float*    w2   = (float*)(ws + 20987904);
    ushort_t* d2   = (ushort_t*)(ws + 21053440);
    float*    pmin = (float*)(ws + 155271168);
    int*      pidx = (int*)(ws + 157368320);
    float*    lossb= (float*)(ws + 159465472);

    k_convert<<<5120, 256, 0, stream>>>(X, W, Xf8, Wf8, x2, w2);
    k_gemm<<<2048, 512, 0, stream>>>(Xf8, Wf8, x2, w2, d2, pmin, pidx);
    k_loss<<<4096, 256, 0, stream>>>(d2, pmin, pidx, lossb);
    k_final<<<1, 256, 0, stream>>>(lossb, (float*)d_out);
}

// Round 17
// 144.265 us; speedup vs baseline: 1.3564x; 1.0995x over previous
//
#include <hip/hip_runtime.h>

// SOM loss, MI355X — FP8 GEMM (k-permuted, compiler-scheduled loop, R16 base)
// + d2 stored as SCALED FP8 (x 1/16, e4m3): halves d2 write + k_loss read traffic.
// B=4096, D=1024, m=n=128, T=100.
// Xf8/Wf8 stored with within-64B-block byte permutation s = ((k>>3)&1)*32 + (k>>4)*8 + (k&7)
// so MFMA fragments are contiguous 16B chunks (ds_read_b128 at floor). Same perm on X and W
// => dot products unchanged.
// ws layout:
//   Xf8  fp8[4096][1024]         @ 0           (4 MB)
//   Wf8  fp8[16384][1024]        @ 4194304     (16 MB)
//   x2   f32[4096]               @ 20971520
//   w2   f32[16384]              @ 20987904
//   d2   fp8[4096][16384] (x1/16)@ 21053440    (64 MB)
//   pmin f32[4096][128]          @ 88162304
//   pidx i32[4096][128]          @ 90259456
//   lossb f32[4096]              @ 92356608

typedef __attribute__((ext_vector_type(8))) short short8;
typedef __attribute__((ext_vector_type(16))) float f32x16;
typedef __attribute__((ext_vector_type(2))) long i64x2;
typedef __attribute__((ext_vector_type(4))) int i32x4;
typedef __attribute__((ext_vector_type(2))) float f32x2;
typedef unsigned short ushort_t;

#define B_ROWS 4096
#define DIM    1024
#define MN     16384
#define NJB    128
#define D2SCALE    0.0625f   // 1/16
#define D2DESCALE  16.0f

__device__ static inline void gload_lds16(const void* g, void* l) {
    __builtin_amdgcn_global_load_lds(
        (const __attribute__((address_space(1))) unsigned*)g,
        (__attribute__((address_space(3))) unsigned*)l, 16, 0, 0);
}

// fp8(e4m3) -> f32 pair decode, preferring HW cvt
__device__ static inline void fp8x4_to_f32(int word, float* out) {
#if __has_builtin(__builtin_amdgcn_cvt_pk_f32_fp8)
    f32x2 lo = __builtin_amdgcn_cvt_pk_f32_fp8(word, false);
    f32x2 hi = __builtin_amdgcn_cvt_pk_f32_fp8(word, true);
    out[0] = lo[0]; out[1] = lo[1]; out[2] = hi[0]; out[3] = hi[1];
#elif __has_builtin(__builtin_amdgcn_cvt_f32_fp8)
    out[0] = __builtin_amdgcn_cvt_f32_fp8(word, 0);
    out[1] = __builtin_amdgcn_cvt_f32_fp8(word, 1);
    out[2] = __builtin_amdgcn_cvt_f32_fp8(word, 2);
    out[3] = __builtin_amdgcn_cvt_f32_fp8(word, 3);
#else
    #pragma unroll
    for (int k = 0; k < 4; ++k) {
        unsigned b = (word >> (8 * k)) & 0xFF;
        unsigned e = (b >> 3) & 0xF, m = b & 7;
        float f = __uint_as_float(((e + 120u) << 23) | (m << 20));
        if (e == 0) f = (float)m * 0.001953125f;     // denormal: m * 2^-9
        out[k] = (b & 0x80) ? -f : f;
    }
#endif
}

// ---------- Kernel 1: f32 -> fp8(e4m3), k-permuted store + row sum-of-squares ----------
__global__ __launch_bounds__(256) void k_convert(
    const float* __restrict__ X, const float* __restrict__ W,
    unsigned char* __restrict__ Xf8, unsigned char* __restrict__ Wf8,
    float* __restrict__ x2, float* __restrict__ w2) {
    int row  = blockIdx.x * 4 + (threadIdx.x >> 6);
    int lane = threadIdx.x & 63;
    const float4* src;
    int* dst;
    float* sq;
    if (row < B_ROWS) {
        src = (const float4*)(X + (size_t)row * DIM);
        dst = (int*)(Xf8 + (size_t)row * DIM);
        sq  = x2 + row;
    } else {
        int r2 = row - B_ROWS;
        src = (const float4*)(W + (size_t)r2 * DIM);
        dst = (int*)(Wf8 + (size_t)r2 * DIM);
        sq  = w2 + r2;
    }
    const int t4 = lane >> 4;
    const int Foff = ((lane >> 3) & 1) * 2 + ((lane >> 1) & 3) * 4 + (lane & 1);
    float s = 0.f;
    #pragma unroll
    for (int c = 0; c < 4; ++c) {
        int F = (c * 4 + t4) * 16 + Foff;     // float4 index of permuted source
        float4 v = src[F];
        s += v.x * v.x + v.y * v.y + v.z * v.z + v.w * v.w;
        int r = __builtin_amdgcn_cvt_pk_fp8_f32(v.x, v.y, 0, false);
        r     = __builtin_amdgcn_cvt_pk_fp8_f32(v.z, v.w, r, true);
        dst[c * 64 + lane] = r;
    }
    #pragma unroll
    for (int d = 1; d < 64; d <<= 1) s += __shfl_xor(s, d);
    if (lane == 0) *sq = s;
}

// ---------- Kernel 2: 256x128-tile FP8 GEMM (v_mfma_f32_32x32x16_fp8_fp8) ----------
// 512 thr = 8 waves (4M x 2N), wave tile 64x64 (acc 64 f32 AGPR). K-tile 64 fp8.
// LDS: 2 dbuf x 24KB, composite 128B rows, XOR ((crow&7)<<4). 16 K-tiles.
// Hot loop is COMPILER-SCHEDULED (R16): plain ds_reads q0/q1 groups + MFMAs;
// only cross-wave gates kept: BAR / STAGE / vmcnt(3) / BAR.
// Epilogue stores d2 as fp8 (x 1/16) via LDS transpose -> coalesced 64B rows.
__global__ __launch_bounds__(512, 3) void k_gemm(
    const unsigned char* __restrict__ Xf8, const unsigned char* __restrict__ Wf8,
    const float* __restrict__ x2, const float* __restrict__ w2,
    unsigned char* __restrict__ d2, float* __restrict__ pmin, int* __restrict__ pidx) {
    __shared__ __attribute__((aligned(1024))) unsigned char ldsb[65536];

    const int tid  = threadIdx.x;
    const int lane = tid & 63;
    const int w    = tid >> 6;
    const int wrM  = w >> 1;      // 0..3  (X-row quarter of 256)
    const int wcN  = w & 1;       // 0..1  (W-col half of 128)
    const int l31  = lane & 31;
    const int h    = lane >> 5;   // k-half

    // XCD-bijective block swizzle (2048 % 8 == 0)
    const int bid = blockIdx.x;
    const int swz = (bid & 7) * 256 + (bid >> 3);
    const int tn  = swz >> 4;     // 0..127  W-tile (128 cols)
    const int tm  = swz & 15;     // 0..15   X-tile (256 rows)

    const size_t aRow = (size_t)tm * 256;
    const size_t bRow = (size_t)tn * 128;

    // staging source precompute (inverse-swizzled)
    const unsigned char* srcA0; const unsigned char* srcA1; const unsigned char* srcB0;
    {
        int p, crow, lcol;
        p = tid * 16; crow = p >> 7; lcol = (p & 127) ^ ((crow & 7) << 4);
        srcA0 = Xf8 + (aRow + crow * 2 + (lcol >> 6)) * DIM + (lcol & 63);
        p = 8192 + tid * 16; crow = p >> 7; lcol = (p & 127) ^ ((crow & 7) << 4);
        srcA1 = Xf8 + (aRow + crow * 2 + (lcol >> 6)) * DIM + (lcol & 63);
        p = tid * 16; crow = p >> 7; lcol = (p & 127) ^ ((crow & 7) << 4);
        srcB0 = Wf8 + (bRow + crow * 2 + (lcol >> 6)) * DIM + (lcol & 63);
    }

    #define STAGE(kt, buf) do {                                                  \
        gload_lds16(srcA0 + (kt) * 64, ldsb + (buf) * 24576 + tid * 16);         \
        gload_lds16(srcA1 + (kt) * 64, ldsb + (buf) * 24576 + 8192 + tid * 16);  \
        gload_lds16(srcB0 + (kt) * 64, ldsb + (buf) * 24576 + 16384 + tid * 16); \
    } while (0)

    // fragment addressing: row r = base + l31; composite crow = r>>1;
    // stored offset in composite = (r&1)*64 + h*32 + q*16, XOR ((crow&7)<<4).
    const int rA0  = wrM * 64 + l31;
    const int rB0  = wcN * 64 + l31;
    const int fb   = (l31 & 1) * 64 + h * 32;
    const int aA0 = (rA0 >> 1) * 128 + ((fb)      ^ (((rA0 >> 1) & 7) << 4));
    const int aA1 = (rA0 >> 1) * 128 + ((fb + 16) ^ (((rA0 >> 1) & 7) << 4));
    const int aB0 = 16384 + (rB0 >> 1) * 128 + ((fb)      ^ (((rB0 >> 1) & 7) << 4));
    const int aB1 = 16384 + (rB0 >> 1) * 128 + ((fb + 16) ^ (((rB0 >> 1) & 7) << 4));

    f32x16 acc[2][2];
    #pragma unroll
    for (int i = 0; i < 2; ++i)
        #pragma unroll
        for (int j = 0; j < 2; ++j) acc[i][j] = (f32x16)0.f;

    #define BAR() __builtin_amdgcn_s_barrier()

    // prologue: T0 -> buf0, T1 -> buf1
    STAGE(0, 0);
    STAGE(1, 1);
    asm volatile("s_waitcnt vmcnt(3)" ::: "memory");   // T0 landed (T1 in flight)
    BAR();

    for (int kt = 0; kt < 16; ++kt) {
        const int bb = (kt & 1) * 24576;
        i64x2 xq0[2], xq1[2], wq0[2], wq1[2];
        // q0 group first, q1 group second — compiler schedules counted waits
        #pragma unroll
        for (int mi = 0; mi < 2; ++mi)
            xq0[mi] = *(const i64x2*)(ldsb + bb + aA0 + mi * 2048);
        #pragma unroll
        for (int ni = 0; ni < 2; ++ni)
            wq0[ni] = *(const i64x2*)(ldsb + bb + aB0 + ni * 2048);
        #pragma unroll
        for (int mi = 0; mi < 2; ++mi)
            xq1[mi] = *(const i64x2*)(ldsb + bb + aA1 + mi * 2048);
        #pragma unroll
        for (int ni = 0; ni < 2; ++ni)
            wq1[ni] = *(const i64x2*)(ldsb + bb + aB1 + ni * 2048);
        // MFMA q0 (needs only q0 regs) — q1 reads drain underneath
        #pragma unroll
        for (int mi = 0; mi < 2; ++mi)
            #pragma unroll
            for (int ni = 0; ni < 2; ++ni) {
                acc[mi][ni] = __builtin_amdgcn_mfma_f32_32x32x16_fp8_fp8(
                    wq0[ni][0], xq0[mi][0], acc[mi][ni], 0, 0, 0);   // ks0
                acc[mi][ni] = __builtin_amdgcn_mfma_f32_32x32x16_fp8_fp8(
                    wq0[ni][1], xq0[mi][1], acc[mi][ni], 0, 0, 0);   // ks1
            }
        // MFMA q1
        #pragma unroll
        for (int mi = 0; mi < 2; ++mi)
            #pragma unroll
            for (int ni = 0; ni < 2; ++ni) {
                acc[mi][ni] = __builtin_amdgcn_mfma_f32_32x32x16_fp8_fp8(
                    wq1[ni][0], xq1[mi][0], acc[mi][ni], 0, 0, 0);   // ks2
                acc[mi][ni] = __builtin_amdgcn_mfma_f32_32x32x16_fp8_fp8(
                    wq1[ni][1], xq1[mi][1], acc[mi][ni], 0, 0, 0);   // ks3
            }
        BAR();   // all waves' reads of bb consumed (MFMA deps force drain)
        if (kt < 14) {
            STAGE(kt + 2, kt & 1);
            asm volatile("s_waitcnt vmcnt(3)" ::: "memory");  // kt+1 landed
            BAR();
        } else if (kt == 14) {
            asm volatile("s_waitcnt vmcnt(0)" ::: "memory");  // kt=15 landed
            BAR();
        }
    }

    // ---- epilogue: d2 = (x2 - 2*dot + w2) * 1/16 -> fp8, LDS-transposed store ----
    // D layout (32x32, shape-determined): col = l31 (X-row), row = (reg&3)+8*(reg>>2)
    // +4*h (W-col). per-wave 4KB: [xr:64][64B], 16B-granule XOR ((xr&3)<<4)
    unsigned char* wls = ldsb + w * 4096;
    const int colw = tn * 128 + wcN * 64;
    const int rowbase = tm * 256 + wrM * 64;
    float4 w2q[2][4];
    #pragma unroll
    for (int ni = 0; ni < 2; ++ni)
        #pragma unroll
        for (int q = 0; q < 4; ++q)
            w2q[ni][q] = *(const float4*)(w2 + colw + ni * 32 + q * 8 + h * 4);

    float mnA[2]; int ixA[2];
    #pragma unroll
    for (int mi = 0; mi < 2; ++mi) {
        const int xr = mi * 32 + l31;
        const float xx = x2[rowbase + xr];
        float mn = __builtin_inff(); int ix = 0x7fffffff;
        #pragma unroll
        for (int ni = 0; ni < 2; ++ni) {
            #pragma unroll
            for (int q = 0; q < 4; ++q) {
                float dv[4];
                #pragma unroll
                for (int t = 0; t < 4; ++t)
                    dv[t] = xx - 2.f * acc[mi][ni][q * 4 + t] + w2q[ni][q][t];
                int pk = __builtin_amdgcn_cvt_pk_fp8_f32(
                    dv[0] * D2SCALE, dv[1] * D2SCALE, 0, false);
                pk = __builtin_amdgcn_cvt_pk_fp8_f32(
                    dv[2] * D2SCALE, dv[3] * D2SCALE, pk, true);
                const int c = ni * 32 + q * 8 + h * 4;
                *(int*)(wls + xr * 64 + (c ^ ((xr & 3) << 4))) = pk;
                #pragma unroll
                for (int t = 0; t < 4; ++t) {
                    const int cand = colw + c + t;
                    if (dv[t] < mn || (dv[t] == mn && cand < ix)) { mn = dv[t]; ix = cand; }
                }
            }
        }
        float om = __shfl_xor(mn, 32);
        int   oi = __shfl_xor(ix, 32);
        if (om < mn || (om == mn && oi < ix)) { mn = om; ix = oi; }
        mnA[mi] = mn; ixA[mi] = ix;
    }
    // read back transposed: 4 lanes x 16B = 64B contiguous per d2 row
    // (compiler inserts the lgkm waits for the write->read dependency)
    #pragma unroll
    for (int j = 0; j < 4; ++j) {
        const int rl = j * 16 + (lane >> 2);     // row_local 0..63
        const int cb = (lane & 3) * 16;
        i32x4 v = *(const i32x4*)(wls + rl * 64 + (cb ^ ((rl & 3) << 4)));
        *(i32x4*)(d2 + (size_t)(rowbase + rl) * MN + colw + cb) = v;
    }
    __syncthreads();
    // per-row argmin partials across the 2 N-waves
    float* smin = (float*)ldsb;            // [256][2]
    int*   sidx = (int*)(ldsb + 2048);     // [256][2]
    if (lane < 32) {
        #pragma unroll
        for (int mi = 0; mi < 2; ++mi) {
            const int rloc = wrM * 64 + mi * 32 + l31;
            smin[rloc * 2 + wcN] = mnA[mi];
            sidx[rloc * 2 + wcN] = ixA[mi];
        }
    }
    __syncthreads();
    if (tid < 256) {
        float m0 = smin[tid * 2];     int i0 = sidx[tid * 2];
        float m1 = smin[tid * 2 + 1]; int i1 = sidx[tid * 2 + 1];
        bool take1 = (m1 < m0) || (m1 == m0 && i1 < i0);
        const int row = tm * 256 + tid;
        pmin[(size_t)row * NJB + tn] = take1 ? m1 : m0;
        pidx[(size_t)row * NJB + tn] = take1 ? i1 : i0;
    }
    #undef STAGE
    #undef BAR
}

// ---------- Kernel 3: fused argmin-finish + influence-weighted row sum (fp8 d2) ----------
__global__ __launch_bounds__(256) void k_loss(
    const unsigned char* __restrict__ d2, const float* __restrict__ pmin,
    const int* __restrict__ pidx, float* __restrict__ lossb) {
    __shared__ float etab[255];
    __shared__ float red[4];
    __shared__ int bmu_s;
    int t = threadIdx.x;
    if (t < 255) etab[t] = __expf(-(float)(t * t) * 1e-4f);  // exp(-r^2/T^2), T=100
    int row = blockIdx.x;
    if (t < 64) {
        float m0 = pmin[(size_t)row * NJB + t];
        int   i0 = pidx[(size_t)row * NJB + t];
        float m1 = pmin[(size_t)row * NJB + t + 64];
        int   i1 = pidx[(size_t)row * NJB + t + 64];
        if (m1 < m0 || (m1 == m0 && i1 < i0)) { m0 = m1; i0 = i1; }
        #pragma unroll
        for (int d = 1; d < 64; d <<= 1) {
            float om = __shfl_xor(m0, d);
            int   oi = __shfl_xor(i0, d);
            if (om < m0 || (om == m0 && oi < i0)) { m0 = om; i0 = oi; }
        }
        if (t == 0) bmu_s = i0;
    }
    __syncthreads();
    int bl = bmu_s;
    int bi = bl >> 7, bj = bl & 127;
    const unsigned char* dr = d2 + (size_t)row * MN;
    float s = 0.f;
    #pragma unroll
    for (int c = 0; c < 8; ++c) {
        int j = c * 2048 + t * 8;                 // 8 consecutive cells (bytes)
        int2 v = *(const int2*)&dr[j];
        float f[8];
        fp8x4_to_f32(v.x, f);
        fp8x4_to_f32(v.y, f + 4);
        int di = abs((j >> 7) - bi);
        int jc = j & 127;
        #pragma unroll
        for (int u = 0; u < 8; ++u) {
            int mh = di + abs(jc + u - bj);
            s += f[u] * etab[mh];
        }
    }
    #pragma unroll
    for (int d = 1; d < 64; d <<= 1) s += __shfl_xor(s, d);
    if ((t & 63) == 0) red[t >> 6] = s;
    __syncthreads();
    if (t == 0) lossb[row] = D2DESCALE * (red[0] + red[1] + red[2] + red[3]);
}

// ---------- Kernel 4: final deterministic reduce ----------
__global__ __launch_bounds__(256) void k_final(
    const float* __restrict__ lossb, float* __restrict__ out) {
    __shared__ float red[4];
    int t = threadIdx.x;
    float s = 0.f;
    #pragma unroll
    for (int k = 0; k < 16; ++k) s += lossb[t + k * 256];
    #pragma unroll
    for (int d = 1; d < 64; d <<= 1) s += __shfl_xor(s, d);
    if ((t & 63) == 0) red[t >> 6] = s;
    __syncthreads();
    if (t == 0) out[0] = (red[0] + red[1] + red[2] + red[3]) * (1.0f / 128.0f);
}

extern "C" void kernel_launch(void* const* d_in, const int* in_sizes, int n_in,
                              void* d_out, int out_size, void* d_ws, size_t ws_size,
                              hipStream_t stream) {
    const float* X = (const float*)d_in[0];
    const float* W = (const float*)d_in[1];
    unsigned char* ws = (unsigned char*)d_ws;
    unsigned char* Xf8 = ws;
    unsigned char* Wf8 = ws + 4194304;
    float*    x2   = (float*)(ws + 20971520);
    float*    w2   = (float*)(ws + 20987904);
    unsigned char* d2 = ws + 21053440;
    float*    pmin = (float*)(ws + 88162304);
    int*      pidx = (int*)(ws + 90259456);
    float*    lossb= (float*)(ws + 92356608);

    k_convert<<<5120, 256, 0, stream>>>(X, W, Xf8, Wf8, x2, w2);
    k_gemm<<<2048, 512, 0, stream>>>(Xf8, Wf8, x2, w2, d2, pmin, pidx);
    k_loss<<<4096, 256, 0, stream>>>(d2, pmin, pidx, lossb);
    k_final<<<1, 256, 0, stream>>>(lossb, (float*)d_out);
}